// Round 3
// baseline (374.464 us; speedup 1.0000x reference)
//
#include <hip/hip_runtime.h>

namespace {
constexpr unsigned kT  = 1u << 19;
constexpr unsigned kTm = kT - 1u;
constexpr unsigned kP1 = 2654435761u;
constexpr unsigned kP2 = 805459861u;
constexpr int kPPT = 2;            // points per thread
}

typedef float f32x2 __attribute__((ext_vector_type(2)));

// One block = 512 points (2/thread) at ONE level. blockIdx layout gives
// XCD<->level affinity under round-robin dispatch (block i -> XCD i%8):
//   g = i % 8, j = i / 8, phase = j / cpl, level = g + 8*phase
// so XCD g streams level g's 4 MiB table (L2-resident), then level g+8.
// 2 points/thread -> 16 independent gathers in flight (latency-bound fix).
__global__ __launch_bounds__(256) void hashgrid_fwd_lvl2(
    const float* __restrict__ x,
    const float* __restrict__ hashmap,
    const float* __restrict__ resolution,
    f32x2* __restrict__ out,
    int npts, unsigned cpl)
{
    unsigned i = blockIdx.x;
    unsigned g = i & 7u;
    unsigned j = i >> 3;
    unsigned phase = j / cpl;          // uniform scalar division, once/block
    unsigned chunk = j - phase * cpl;
    unsigned l = g + (phase << 3);

    float res = resolution[l];         // uniform -> scalar load
    const f32x2* __restrict__ tb =
        reinterpret_cast<const f32x2*>(hashmap) + (size_t)l * kT;

    int nbase = (int)(chunk * (256u * kPPT) + threadIdx.x);

    int   nn[kPPT];
    bool  ok[kPPT];
    float wx[kPPT], wy[kPPT], wz[kPPT];
    unsigned idx[kPPT][8];
    f32x2 f[kPPT][8];

    #pragma unroll
    for (int p = 0; p < kPPT; ++p) {
        int n = nbase + p * 256;
        nn[p] = n;
        ok[p] = (n < npts);
        int ns = ok[p] ? n : 0;

        float px = __builtin_nontemporal_load(&x[3*ns+0]);
        float py = __builtin_nontemporal_load(&x[3*ns+1]);
        float pz = __builtin_nontemporal_load(&x[3*ns+2]);

        float xs = px*res, ys = py*res, zs = pz*res;
        float fx = floorf(xs), fy = floorf(ys), fz = floorf(zs);
        wx[p] = xs-fx; wy[p] = ys-fy; wz[p] = zs-fz;

        unsigned cx0 = (unsigned)fx;
        unsigned cy0 = (unsigned)fy;
        unsigned cz0 = (unsigned)fz;
        unsigned hx0 = cx0,          hx1 = cx0 + 1u;
        unsigned hy0 = cy0 * kP1,    hy1 = (cy0 + 1u) * kP1;
        unsigned hz0 = cz0 * kP2,    hz1 = (cz0 + 1u) * kP2;

        idx[p][0] = (hx0 ^ hy0 ^ hz0) & kTm;
        idx[p][1] = (hx0 ^ hy0 ^ hz1) & kTm;
        idx[p][2] = (hx0 ^ hy1 ^ hz0) & kTm;
        idx[p][3] = (hx0 ^ hy1 ^ hz1) & kTm;
        idx[p][4] = (hx1 ^ hy0 ^ hz0) & kTm;
        idx[p][5] = (hx1 ^ hy0 ^ hz1) & kTm;
        idx[p][6] = (hx1 ^ hy1 ^ hz0) & kTm;
        idx[p][7] = (hx1 ^ hy1 ^ hz1) & kTm;
    }

    // 16 independent gathers, all issued before any use
    #pragma unroll
    for (int p = 0; p < kPPT; ++p)
        #pragma unroll
        for (int c = 0; c < 8; ++c)
            f[p][c] = tb[idx[p][c]];

    #pragma unroll
    for (int p = 0; p < kPPT; ++p) {
        float wxn = 1.f - wx[p], wyn = 1.f - wy[p], wzn = 1.f - wz[p];
        float w000 = wxn*wyn*wzn, w001 = wxn*wyn*wz[p];
        float w010 = wxn*wy[p]*wzn, w011 = wxn*wy[p]*wz[p];
        float w100 = wx[p]*wyn*wzn, w101 = wx[p]*wyn*wz[p];
        float w110 = wx[p]*wy[p]*wzn, w111 = wx[p]*wy[p]*wz[p];

        f32x2 o;
        o.x = w000*f[p][0].x + w001*f[p][1].x + w010*f[p][2].x + w011*f[p][3].x
            + w100*f[p][4].x + w101*f[p][5].x + w110*f[p][6].x + w111*f[p][7].x;
        o.y = w000*f[p][0].y + w001*f[p][1].y + w010*f[p][2].y + w011*f[p][3].y
            + w100*f[p][4].y + w101*f[p][5].y + w110*f[p][6].y + w111*f[p][7].y;

        if (ok[p])
            __builtin_nontemporal_store(o, &out[(size_t)nn[p]*16 + l]);
    }
}

extern "C" void kernel_launch(void* const* d_in, const int* in_sizes, int n_in,
                              void* d_out, int out_size, void* d_ws, size_t ws_size,
                              hipStream_t stream) {
    const float* x          = (const float*)d_in[0];
    const float* hashmap    = (const float*)d_in[1];
    const float* resolution = (const float*)d_in[2];
    f32x2* out = (f32x2*)d_out;

    int npts = in_sizes[0] / 3;
    unsigned ppb = 256u * kPPT;                        // points per block
    unsigned cpl = (unsigned)((npts + ppb - 1) / ppb); // chunks per level
    unsigned blocks = 16u * cpl;                       // 16 levels
    hashgrid_fwd_lvl2<<<blocks, 256, 0, stream>>>(x, hashmap, resolution, out,
                                                  npts, cpl);
}

// Round 4
// 368.468 us; speedup vs baseline: 1.0163x; 1.0163x over previous
//
#include <hip/hip_runtime.h>

namespace {
constexpr unsigned kT  = 1u << 19;
constexpr unsigned kTm = kT - 1u;
constexpr unsigned kP1 = 2654435761u;
constexpr unsigned kP2 = 805459861u;

// ---- dense cell-block tables for coarse levels 0..2 (res 16,22,30) ----
constexpr int      kD[3]    = {17, 23, 31};                 // cells per axis (cover c0=0..r)
constexpr unsigned kC[3]    = {17u*17u*17u, 23u*23u*23u, 31u*31u*31u};
constexpr unsigned kBase[3] = {0u, kC[0]*8u, (kC[0]+kC[1])*8u};   // in f32x2 elems
constexpr unsigned kTotElems = (kC[0]+kC[1]+kC[2])*8u;            // 374968 f32x2
constexpr size_t   kWsBytes  = (size_t)kTotElems * 8u;            // ~3.0 MB

// ---- cost-balanced (level, chunk-range) schedule per XCD ----
// chunk = 256 points; 2048 chunks/level; coarse cost 1.4, fine cost 8.
constexpr unsigned kCPL = 2048;
constexpr int kNSeg[8]      = {5,2,3,3,2,3,3,2};
constexpr int kSegLvl[8][5] = {
  {0,1,2,3,4}, {4,5,0,0,0}, {5,6,7,0,0}, {7,8,9,0,0},
  {9,10,0,0,0}, {10,11,12,0,0}, {12,13,14,0,0}, {14,15,0,0,0}};
constexpr int kSegBeg[8][5] = {
  {0,0,0,0,0}, {339,0,0,0,0}, {1754,0,0,0,0}, {1120,0,0,0,0},
  {486,0,0,0,0}, {1900,0,0,0,0}, {1266,0,0,0,0}, {632,0,0,0,0}};
constexpr int kSegEnd[8][5] = {
  {2048,2048,2048,2048,339}, {2048,1754,0,0,0}, {2048,2048,1120,0,0},
  {2048,2048,486,0,0}, {2048,1900,0,0,0}, {2048,2048,1266,0,0},
  {2048,2048,632,0,0}, {2048,2048,0,0,0}};
constexpr unsigned kMaxBlk = 8531;          // XCD0's block count (largest)
}

typedef float f32x2 __attribute__((ext_vector_type(2)));

// Build dense per-cell corner blocks for levels 0..2:
// dense[base_l + cell*8 + corner] = hashmap[l][hash(cell+corner_offset)]
__global__ __launch_bounds__(256) void build_dense(
    const float* __restrict__ hashmap, f32x2* __restrict__ dense)
{
    unsigned t = blockIdx.x * 256 + threadIdx.x;
    if (t >= kTotElems) return;
    int l; unsigned rem;
    if (t < kC[0]*8u)              { l = 0; rem = t; }
    else if (t < (kC[0]+kC[1])*8u) { l = 1; rem = t - kC[0]*8u; }
    else                           { l = 2; rem = t - (kC[0]+kC[1])*8u; }
    unsigned cell = rem >> 3, corner = rem & 7u;
    unsigned D = (unsigned)kD[l];
    unsigned ck = cell % D, tmp = cell / D;
    unsigned cj = tmp % D,  ci = tmp / D;
    unsigned ii = ci + ((corner >> 2) & 1u);
    unsigned jj = cj + ((corner >> 1) & 1u);
    unsigned kk = ck + (corner & 1u);
    unsigned h = (ii ^ (jj * kP1) ^ (kk * kP2)) & kTm;
    dense[t] = reinterpret_cast<const f32x2*>(hashmap)[(size_t)l * kT + h];
}

__global__ __launch_bounds__(256) void hashgrid_sched(
    const float* __restrict__ x,
    const float* __restrict__ hashmap,
    const float* __restrict__ resolution,
    const f32x2* __restrict__ dense,
    f32x2* __restrict__ out,
    int npts)
{
    unsigned i = blockIdx.x;
    unsigned g = i & 7u;        // XCD under round-robin dispatch
    unsigned j = i >> 3;        // per-XCD block ordinal

    int lvl = -1; unsigned chunk = 0, acc = 0;
    #pragma unroll
    for (int s = 0; s < 5; ++s) {
        if (s >= kNSeg[g]) break;
        unsigned len = (unsigned)(kSegEnd[g][s] - kSegBeg[g][s]);
        if (j < acc + len) { lvl = kSegLvl[g][s]; chunk = kSegBeg[g][s] + (j - acc); break; }
        acc += len;
    }
    if (lvl < 0) return;

    int n = (int)(chunk * 256u + threadIdx.x);
    if (n >= npts) return;

    float px = __builtin_nontemporal_load(&x[3*n+0]);
    float py = __builtin_nontemporal_load(&x[3*n+1]);
    float pz = __builtin_nontemporal_load(&x[3*n+2]);
    float res = resolution[lvl];

    float xs = px*res, ys = py*res, zs = pz*res;
    float fx = floorf(xs), fy = floorf(ys), fz = floorf(zs);
    float wx = xs-fx, wy = ys-fy, wz = zs-fz;

    unsigned cx0 = (unsigned)fx;
    unsigned cy0 = (unsigned)fy;
    unsigned cz0 = (unsigned)fz;

    float f0x,f0y,f1x,f1y,f2x,f2y,f3x,f3y,f4x,f4y,f5x,f5y,f6x,f6y,f7x,f7y;

    if (lvl < 3) {
        // dense path: one 64B cell block = 4x float4 from the same line
        unsigned D = (unsigned)kD[lvl];
        size_t cellIdx = ((size_t)cx0 * D + cy0) * D + cz0;
        const float4* blk = reinterpret_cast<const float4*>(
            dense + kBase[lvl] + cellIdx * 8u);
        float4 q0 = blk[0], q1 = blk[1], q2 = blk[2], q3 = blk[3];
        f0x=q0.x; f0y=q0.y; f1x=q0.z; f1y=q0.w;
        f2x=q1.x; f2y=q1.y; f3x=q1.z; f3y=q1.w;
        f4x=q2.x; f4y=q2.y; f5x=q2.z; f5y=q2.w;
        f6x=q3.x; f6y=q3.y; f7x=q3.z; f7y=q3.w;
    } else {
        unsigned hx0 = cx0,       hx1 = cx0 + 1u;
        unsigned hy0 = cy0 * kP1, hy1 = (cy0 + 1u) * kP1;
        unsigned hz0 = cz0 * kP2, hz1 = (cz0 + 1u) * kP2;
        const f32x2* __restrict__ tb =
            reinterpret_cast<const f32x2*>(hashmap) + (size_t)lvl * kT;
        f32x2 f000 = tb[(hx0 ^ hy0 ^ hz0) & kTm];
        f32x2 f001 = tb[(hx0 ^ hy0 ^ hz1) & kTm];
        f32x2 f010 = tb[(hx0 ^ hy1 ^ hz0) & kTm];
        f32x2 f011 = tb[(hx0 ^ hy1 ^ hz1) & kTm];
        f32x2 f100 = tb[(hx1 ^ hy0 ^ hz0) & kTm];
        f32x2 f101 = tb[(hx1 ^ hy0 ^ hz1) & kTm];
        f32x2 f110 = tb[(hx1 ^ hy1 ^ hz0) & kTm];
        f32x2 f111 = tb[(hx1 ^ hy1 ^ hz1) & kTm];
        f0x=f000.x; f0y=f000.y; f1x=f001.x; f1y=f001.y;
        f2x=f010.x; f2y=f010.y; f3x=f011.x; f3y=f011.y;
        f4x=f100.x; f4y=f100.y; f5x=f101.x; f5y=f101.y;
        f6x=f110.x; f6y=f110.y; f7x=f111.x; f7y=f111.y;
    }

    float wxn = 1.f - wx, wyn = 1.f - wy, wzn = 1.f - wz;
    float w000 = wxn*wyn*wzn, w001 = wxn*wyn*wz;
    float w010 = wxn*wy *wzn, w011 = wxn*wy *wz;
    float w100 = wx *wyn*wzn, w101 = wx *wyn*wz;
    float w110 = wx *wy *wzn, w111 = wx *wy *wz;

    f32x2 o;
    o.x = w000*f0x + w001*f1x + w010*f2x + w011*f3x
        + w100*f4x + w101*f5x + w110*f6x + w111*f7x;
    o.y = w000*f0y + w001*f1y + w010*f2y + w011*f3y
        + w100*f4y + w101*f5y + w110*f6y + w111*f7y;

    __builtin_nontemporal_store(o, &out[(size_t)n*16 + lvl]);
}

// fallback (round-2 kernel): used if ws too small or unexpected npts
__global__ __launch_bounds__(256) void hashgrid_fwd_lvl(
    const float* __restrict__ x,
    const float* __restrict__ hashmap,
    const float* __restrict__ resolution,
    f32x2* __restrict__ out,
    int npts, unsigned cpl)
{
    unsigned i = blockIdx.x;
    unsigned g = i & 7u;
    unsigned j = i >> 3;
    unsigned phase = j / cpl;
    unsigned chunk = j - phase * cpl;
    unsigned l = g + (phase << 3);

    int n = (int)(chunk * 256u + threadIdx.x);
    if (n >= npts) return;

    float px = __builtin_nontemporal_load(&x[3*n+0]);
    float py = __builtin_nontemporal_load(&x[3*n+1]);
    float pz = __builtin_nontemporal_load(&x[3*n+2]);
    float res = resolution[l];

    float xs = px*res, ys = py*res, zs = pz*res;
    float fx = floorf(xs), fy = floorf(ys), fz = floorf(zs);
    float wx = xs-fx, wy = ys-fy, wz = zs-fz;

    unsigned cx0 = (unsigned)fx, cy0 = (unsigned)fy, cz0 = (unsigned)fz;
    unsigned hx0 = cx0,       hx1 = cx0 + 1u;
    unsigned hy0 = cy0 * kP1, hy1 = (cy0 + 1u) * kP1;
    unsigned hz0 = cz0 * kP2, hz1 = (cz0 + 1u) * kP2;

    const f32x2* __restrict__ tb =
        reinterpret_cast<const f32x2*>(hashmap) + (size_t)l * kT;
    f32x2 f000 = tb[(hx0 ^ hy0 ^ hz0) & kTm];
    f32x2 f001 = tb[(hx0 ^ hy0 ^ hz1) & kTm];
    f32x2 f010 = tb[(hx0 ^ hy1 ^ hz0) & kTm];
    f32x2 f011 = tb[(hx0 ^ hy1 ^ hz1) & kTm];
    f32x2 f100 = tb[(hx1 ^ hy0 ^ hz0) & kTm];
    f32x2 f101 = tb[(hx1 ^ hy0 ^ hz1) & kTm];
    f32x2 f110 = tb[(hx1 ^ hy1 ^ hz0) & kTm];
    f32x2 f111 = tb[(hx1 ^ hy1 ^ hz1) & kTm];

    float wxn = 1.f - wx, wyn = 1.f - wy, wzn = 1.f - wz;
    float w000 = wxn*wyn*wzn, w001 = wxn*wyn*wz;
    float w010 = wxn*wy *wzn, w011 = wxn*wy *wz;
    float w100 = wx *wyn*wzn, w101 = wx *wyn*wz;
    float w110 = wx *wy *wzn, w111 = wx *wy *wz;

    f32x2 o;
    o.x = w000*f000.x + w001*f001.x + w010*f010.x + w011*f011.x
        + w100*f100.x + w101*f101.x + w110*f110.x + w111*f111.x;
    o.y = w000*f000.y + w001*f001.y + w010*f010.y + w011*f011.y
        + w100*f100.y + w101*f101.y + w110*f110.y + w111*f111.y;

    __builtin_nontemporal_store(o, &out[(size_t)n*16 + l]);
}

extern "C" void kernel_launch(void* const* d_in, const int* in_sizes, int n_in,
                              void* d_out, int out_size, void* d_ws, size_t ws_size,
                              hipStream_t stream) {
    const float* x          = (const float*)d_in[0];
    const float* hashmap    = (const float*)d_in[1];
    const float* resolution = (const float*)d_in[2];
    f32x2* out = (f32x2*)d_out;

    int npts = in_sizes[0] / 3;
    unsigned cpl = (unsigned)((npts + 255) / 256);

    if (cpl == kCPL && ws_size >= kWsBytes && d_ws != nullptr) {
        f32x2* dense = (f32x2*)d_ws;
        unsigned pb = (kTotElems + 255u) / 256u;
        build_dense<<<pb, 256, 0, stream>>>(hashmap, dense);
        hashgrid_sched<<<8u * kMaxBlk, 256, 0, stream>>>(
            x, hashmap, resolution, dense, out, npts);
    } else {
        unsigned blocks = 16u * cpl;
        hashgrid_fwd_lvl<<<blocks, 256, 0, stream>>>(x, hashmap, resolution, out,
                                                     npts, cpl);
    }
}

// Round 7
// 241.102 us; speedup vs baseline: 1.5531x; 1.5283x over previous
//
#include <hip/hip_runtime.h>

namespace {
constexpr unsigned kT  = 1u << 19;
constexpr unsigned kTm = kT - 1u;
constexpr unsigned kP1 = 2654435761u;
constexpr unsigned kP2 = 805459861u;
constexpr int      kNPTS = 524288;

// ---- dense cell-block tables for coarse levels 0..2 (res 16,22,30) ----
constexpr int      kD[3]    = {17, 23, 31};
constexpr unsigned kC[3]    = {17u*17u*17u, 23u*23u*23u, 31u*31u*31u};
constexpr unsigned kBase[3] = {0u, kC[0]*8u, (kC[0]+kC[1])*8u};   // f32x2 elems
constexpr unsigned kTotElems = (kC[0]+kC[1]+kC[2])*8u;            // ~375K f32x2
constexpr size_t   kStageOff   = (size_t)4u << 20;                // stage @ +4MB
constexpr size_t   kStageBytes = (size_t)kNPTS * 16u * 8u;        // 64 MB
constexpr size_t   kWsNeed     = kStageOff + kStageBytes;

// ---- cost-balanced schedule: coarse chunk 1.4, fine(pair-merged) chunk 6 ----
constexpr int kNSeg[8]      = {5,2,3,3,2,3,3,2};
constexpr int kSegLvl[8][5] = {
  {0,1,2,3,4}, {4,5,0,0,0}, {5,6,7,0,0}, {7,8,9,0,0},
  {9,10,0,0,0}, {10,11,12,0,0}, {12,13,14,0,0}, {14,15,0,0,0}};
constexpr int kSegBeg[8][5] = {
  {0,0,0,0,0}, {26,0,0,0,0}, {1485,0,0,0,0}, {896,0,0,0,0},
  {307,0,0,0,0}, {1766,0,0,0,0}, {1177,0,0,0,0}, {589,0,0,0,0}};
constexpr int kSegEnd[8][5] = {
  {2048,2048,2048,2048,26}, {2048,1485,0,0,0}, {2048,2048,896,0,0},
  {2048,2048,307,0,0}, {2048,1766,0,0,0}, {2048,2048,1177,0,0},
  {2048,2048,589,0,0}, {2048,2048,0,0,0}};
constexpr unsigned kMaxBlk = 8218;   // XCD0 block count (largest)
}

typedef float f32x2 __attribute__((ext_vector_type(2)));
typedef float f32x4 __attribute__((ext_vector_type(4)));

// Build dense per-cell 64B corner blocks for levels 0..2.
__global__ __launch_bounds__(256) void build_dense(
    const float* __restrict__ hashmap, f32x2* __restrict__ dense)
{
    unsigned t = blockIdx.x * 256 + threadIdx.x;
    if (t >= kTotElems) return;
    int l; unsigned rem;
    if (t < kC[0]*8u)              { l = 0; rem = t; }
    else if (t < (kC[0]+kC[1])*8u) { l = 1; rem = t - kC[0]*8u; }
    else                           { l = 2; rem = t - (kC[0]+kC[1])*8u; }
    unsigned cell = rem >> 3, corner = rem & 7u;
    unsigned D = (unsigned)kD[l];
    unsigned ck = cell % D, tmp = cell / D;
    unsigned cj = tmp % D,  ci = tmp / D;
    unsigned ii = ci + ((corner >> 2) & 1u);
    unsigned jj = cj + ((corner >> 1) & 1u);
    unsigned kk = ck + (corner & 1u);
    unsigned h = (ii ^ (jj * kP1) ^ (kk * kP2)) & kTm;
    dense[t] = reinterpret_cast<const f32x2*>(hashmap)[(size_t)l * kT + h];
}

// Phase A: gather + interpolate, store LEVEL-MAJOR to stage (coalesced, nt).
__global__ __launch_bounds__(256) void hashgrid_gather(
    const float* __restrict__ x,
    const float* __restrict__ hashmap,
    const float* __restrict__ resolution,
    const f32x2* __restrict__ dense,
    f32x2* __restrict__ stage)
{
    unsigned i = blockIdx.x;
    unsigned g = i & 7u;        // XCD under round-robin dispatch
    unsigned j = i >> 3;

    int lvl = -1; unsigned chunk = 0, acc = 0;
    #pragma unroll
    for (int s = 0; s < 5; ++s) {
        if (s >= kNSeg[g]) break;
        unsigned len = (unsigned)(kSegEnd[g][s] - kSegBeg[g][s]);
        if (j < acc + len) { lvl = kSegLvl[g][s]; chunk = kSegBeg[g][s] + (j - acc); break; }
        acc += len;
    }
    if (lvl < 0) return;

    int n = (int)(chunk * 256u + threadIdx.x);

    float px = __builtin_nontemporal_load(&x[3*n+0]);
    float py = __builtin_nontemporal_load(&x[3*n+1]);
    float pz = __builtin_nontemporal_load(&x[3*n+2]);
    float res = resolution[lvl];

    float xs = px*res, ys = py*res, zs = pz*res;
    float fx = floorf(xs), fy = floorf(ys), fz = floorf(zs);
    float wx = xs-fx, wy = ys-fy, wz = zs-fz;

    unsigned cx0 = (unsigned)fx;
    unsigned cy0 = (unsigned)fy;
    unsigned cz0 = (unsigned)fz;

    f32x2 f000, f001, f010, f011, f100, f101, f110, f111;

    if (lvl < 3) {
        // dense path: one 64B cell block = 4x f32x4 from the same line
        unsigned D = (unsigned)kD[lvl];
        size_t cellIdx = ((size_t)cx0 * D + cy0) * D + cz0;
        const f32x4* blk = reinterpret_cast<const f32x4*>(
            dense + kBase[lvl] + cellIdx * 8u);
        f32x4 q0 = blk[0], q1 = blk[1], q2 = blk[2], q3 = blk[3];
        f000 = {q0.x,q0.y}; f001 = {q0.z,q0.w};
        f010 = {q1.x,q1.y}; f011 = {q1.z,q1.w};
        f100 = {q2.x,q2.y}; f101 = {q2.z,q2.w};
        f110 = {q3.x,q3.y}; f111 = {q3.z,q3.w};
    } else {
        unsigned hy0 = cy0 * kP1, hy1 = (cy0 + 1u) * kP1;
        unsigned hz0 = cz0 * kP2, hz1 = (cz0 + 1u) * kP2;
        unsigned hyz00 = hy0 ^ hz0, hyz01 = hy0 ^ hz1;
        unsigned hyz10 = hy1 ^ hz0, hyz11 = hy1 ^ hz1;
        const f32x2* __restrict__ tb =
            reinterpret_cast<const f32x2*>(hashmap) + (size_t)lvl * kT;

        if ((cx0 & 1u) == 0u) {
            // hx1 = hx0 ^ 1 -> x-pair {i, i^1} lives in one aligned 16B slot
            const f32x4* __restrict__ tb4 = reinterpret_cast<const f32x4*>(tb);
            unsigned i00 = (cx0 ^ hyz00) & kTm;
            unsigned i01 = (cx0 ^ hyz01) & kTm;
            unsigned i10 = (cx0 ^ hyz10) & kTm;
            unsigned i11 = (cx0 ^ hyz11) & kTm;
            f32x4 q00 = tb4[i00 >> 1];
            f32x4 q01 = tb4[i01 >> 1];
            f32x4 q10 = tb4[i10 >> 1];
            f32x4 q11 = tb4[i11 >> 1];
            bool o0 = (i00 & 1u), o1 = (i01 & 1u), o2 = (i10 & 1u), o3 = (i11 & 1u);
            f000.x = o0 ? q00.z : q00.x; f000.y = o0 ? q00.w : q00.y;
            f100.x = o0 ? q00.x : q00.z; f100.y = o0 ? q00.y : q00.w;
            f001.x = o1 ? q01.z : q01.x; f001.y = o1 ? q01.w : q01.y;
            f101.x = o1 ? q01.x : q01.z; f101.y = o1 ? q01.y : q01.w;
            f010.x = o2 ? q10.z : q10.x; f010.y = o2 ? q10.w : q10.y;
            f110.x = o2 ? q10.x : q10.z; f110.y = o2 ? q10.y : q10.w;
            f011.x = o3 ? q11.z : q11.x; f011.y = o3 ? q11.w : q11.y;
            f111.x = o3 ? q11.x : q11.z; f111.y = o3 ? q11.y : q11.w;
        } else {
            unsigned hx0 = cx0, hx1 = cx0 + 1u;
            f000 = tb[(hx0 ^ hyz00) & kTm];
            f001 = tb[(hx0 ^ hyz01) & kTm];
            f010 = tb[(hx0 ^ hyz10) & kTm];
            f011 = tb[(hx0 ^ hyz11) & kTm];
            f100 = tb[(hx1 ^ hyz00) & kTm];
            f101 = tb[(hx1 ^ hyz01) & kTm];
            f110 = tb[(hx1 ^ hyz10) & kTm];
            f111 = tb[(hx1 ^ hyz11) & kTm];
        }
    }

    float wxn = 1.f - wx, wyn = 1.f - wy, wzn = 1.f - wz;
    float w000 = wxn*wyn*wzn, w001 = wxn*wyn*wz;
    float w010 = wxn*wy *wzn, w011 = wxn*wy *wz;
    float w100 = wx *wyn*wzn, w101 = wx *wyn*wz;
    float w110 = wx *wy *wzn, w111 = wx *wy *wz;

    f32x2 o;
    o.x = w000*f000.x + w001*f001.x + w010*f010.x + w011*f011.x
        + w100*f100.x + w101*f101.x + w110*f110.x + w111*f111.x;
    o.y = w000*f000.y + w001*f001.y + w010*f010.y + w011*f011.y
        + w100*f100.y + w101*f101.y + w110*f110.y + w111*f111.y;

    // LEVEL-MAJOR staging store: lanes consecutive -> 512B/wave, no RMW lines
    __builtin_nontemporal_store(o, &stage[(size_t)lvl * kNPTS + n]);
}

// Phase B: transpose stage[l][n] -> out[n][l] via LDS tiles, both sides coalesced.
// Each point's out row = 16 levels * f32x2 = 8 f32x4 slots.
__global__ __launch_bounds__(256) void stage_transpose(
    const f32x2* __restrict__ stage, f32x4* __restrict__ out4)
{
    __shared__ f32x2 tile[128][17];
    unsigned n0 = blockIdx.x * 128u;
    unsigned t = threadIdx.x;

    #pragma unroll
    for (int it = 0; it < 8; ++it) {
        unsigned m = (unsigned)it * 256u + t;     // 0..2047
        unsigned l = m >> 7, p = m & 127u;
        tile[p][l] = stage[(size_t)l * kNPTS + n0 + p];
    }
    __syncthreads();

    #pragma unroll
    for (int it = 0; it < 4; ++it) {
        unsigned v = (unsigned)it * 256u + t;     // 0..1023
        unsigned p = v >> 3, q = v & 7u;          // point (0..127), f32x4 slot (0..7)
        f32x2 a = tile[p][2u*q], b = tile[p][2u*q + 1u];
        f32x4 w; w.x = a.x; w.y = a.y; w.z = b.x; w.w = b.y;
        __builtin_nontemporal_store(w, &out4[(size_t)(n0 + p) * 8u + q]);
    }
}

// Fallback (round-2 kernel): direct out, used if ws too small / unexpected npts
__global__ __launch_bounds__(256) void hashgrid_fwd_lvl(
    const float* __restrict__ x,
    const float* __restrict__ hashmap,
    const float* __restrict__ resolution,
    f32x2* __restrict__ out,
    int npts, unsigned cpl)
{
    unsigned i = blockIdx.x;
    unsigned g = i & 7u;
    unsigned j = i >> 3;
    unsigned phase = j / cpl;
    unsigned chunk = j - phase * cpl;
    unsigned l = g + (phase << 3);

    int n = (int)(chunk * 256u + threadIdx.x);
    if (n >= npts) return;

    float px = x[3*n+0], py = x[3*n+1], pz = x[3*n+2];
    float res = resolution[l];

    float xs = px*res, ys = py*res, zs = pz*res;
    float fx = floorf(xs), fy = floorf(ys), fz = floorf(zs);
    float wx = xs-fx, wy = ys-fy, wz = zs-fz;

    unsigned cx0 = (unsigned)fx, cy0 = (unsigned)fy, cz0 = (unsigned)fz;
    unsigned hx0 = cx0,       hx1 = cx0 + 1u;
    unsigned hy0 = cy0 * kP1, hy1 = (cy0 + 1u) * kP1;
    unsigned hz0 = cz0 * kP2, hz1 = (cz0 + 1u) * kP2;

    const f32x2* __restrict__ tb =
        reinterpret_cast<const f32x2*>(hashmap) + (size_t)l * kT;
    f32x2 f000 = tb[(hx0 ^ hy0 ^ hz0) & kTm];
    f32x2 f001 = tb[(hx0 ^ hy0 ^ hz1) & kTm];
    f32x2 f010 = tb[(hx0 ^ hy1 ^ hz0) & kTm];
    f32x2 f011 = tb[(hx0 ^ hy1 ^ hz1) & kTm];
    f32x2 f100 = tb[(hx1 ^ hy0 ^ hz0) & kTm];
    f32x2 f101 = tb[(hx1 ^ hy0 ^ hz1) & kTm];
    f32x2 f110 = tb[(hx1 ^ hy1 ^ hz0) & kTm];
    f32x2 f111 = tb[(hx1 ^ hy1 ^ hz1) & kTm];

    float wxn = 1.f - wx, wyn = 1.f - wy, wzn = 1.f - wz;
    float w000 = wxn*wyn*wzn, w001 = wxn*wyn*wz;
    float w010 = wxn*wy *wzn, w011 = wxn*wy *wz;
    float w100 = wx *wyn*wzn, w101 = wx *wyn*wz;
    float w110 = wx *wy *wzn, w111 = wx *wy *wz;

    f32x2 o;
    o.x = w000*f000.x + w001*f001.x + w010*f010.x + w011*f011.x
        + w100*f100.x + w101*f101.x + w110*f110.x + w111*f111.x;
    o.y = w000*f000.y + w001*f001.y + w010*f010.y + w011*f011.y
        + w100*f100.y + w101*f101.y + w110*f110.y + w111*f111.y;

    __builtin_nontemporal_store(o, &out[(size_t)n*16 + l]);
}

extern "C" void kernel_launch(void* const* d_in, const int* in_sizes, int n_in,
                              void* d_out, int out_size, void* d_ws, size_t ws_size,
                              hipStream_t stream) {
    const float* x          = (const float*)d_in[0];
    const float* hashmap    = (const float*)d_in[1];
    const float* resolution = (const float*)d_in[2];

    int npts = in_sizes[0] / 3;

    if (npts == kNPTS && d_ws != nullptr && ws_size >= kWsNeed) {
        f32x2* dense = (f32x2*)d_ws;
        f32x2* stage = (f32x2*)((char*)d_ws + kStageOff);
        unsigned pb = (kTotElems + 255u) / 256u;
        build_dense<<<pb, 256, 0, stream>>>(hashmap, dense);
        hashgrid_gather<<<8u * kMaxBlk, 256, 0, stream>>>(
            x, hashmap, resolution, dense, stage);
        stage_transpose<<<kNPTS / 128, 256, 0, stream>>>(
            stage, (f32x4*)d_out);
    } else {
        unsigned cpl = (unsigned)((npts + 255) / 256);
        unsigned blocks = 16u * cpl;
        hashgrid_fwd_lvl<<<blocks, 256, 0, stream>>>(
            x, hashmap, resolution, (f32x2*)d_out, npts, cpl);
    }
}